// Round 4
// baseline (1175.252 us; speedup 1.0000x reference)
//
#include <hip/hip_runtime.h>
#include <hip/hip_bf16.h>

// Problem constants
#define H_    128
#define IN_   93
#define NL_   4
#define B_    256
#define T_    512
#define G_    512   // 4*H
#define C_    64    // chunk length (timesteps per launch)
#define NCH   (T_ / C_)          // 8 chunks
#define NLAUNCH (NCH + NL_ - 1)  // 11 wavefront launches
#define LOG2E 1.44269504088896f

#define STR_  260   // LDS row stride in ushorts: 130 dwords ≡ 2 (mod 32) -> 2-way banks (free)

typedef __attribute__((ext_vector_type(8))) short bf16x8;
typedef __attribute__((ext_vector_type(4))) float f32x4;
typedef unsigned long long u64;

#define RCHUNK ((size_t)C_ * B_ * H_)   // elems per ring slot (one chunk of h)

__device__ __forceinline__ ushort bf16_rn(float f) {
    uint x = __float_as_uint(f);
    uint r = (x + 0x7FFFu + ((x >> 16) & 1u)) >> 16;
    return (ushort)r;
}
__device__ __forceinline__ float exp2_fast(float x) { return __builtin_amdgcn_exp2f(x); }
__device__ __forceinline__ float rcp_fast(float x)  { return __builtin_amdgcn_rcpf(x); }

// ---------------------------------------------------------------------------
// prep_x: x [B][T][93] f32 -> xb [T][B][96] bf16 (zero-padded)
// ---------------------------------------------------------------------------
__global__ void prep_x(const float* __restrict__ x, ushort* __restrict__ xb) {
    int idx = blockIdx.x * 256 + threadIdx.x;
    int t = idx / (B_ * 96);
    int rem = idx % (B_ * 96);
    int b = rem / 96;
    int k = rem % 96;
    float v = 0.0f;
    if (k < IN_) v = x[((size_t)b * T_ + t) * IN_ + k];
    xb[idx] = bf16_rn(v);
}

// ---------------------------------------------------------------------------
// prep_w: combined prescaled bf16 weights Wc [NL][512][256]
// ---------------------------------------------------------------------------
__global__ void prep_w(const float* __restrict__ Wih0,
                       const float* __restrict__ Wihr,
                       const float* __restrict__ Whh,
                       ushort* __restrict__ Wc) {
    int idx = blockIdx.x * 256 + threadIdx.x;
    int l = idx / (G_ * 256);
    int rem = idx % (G_ * 256);
    int g = rem / 256;
    int k = rem % 256;
    int kx = (l == 0) ? 96 : 128;
    float v = 0.0f;
    if (k < kx) {
        if (l == 0) { if (k < IN_) v = Wih0[g * IN_ + k]; }
        else        { v = Wihr[(((size_t)(l - 1)) * G_ + g) * H_ + k]; }
    } else if (k < kx + H_) {
        v = Whh[(((size_t)l) * G_ + g) * H_ + (k - kx)];
    }
    float scale = (g >= 256 && g < 384) ? (2.0f * LOG2E) : LOG2E;
    Wc[idx] = bf16_rn(v * scale);
}

__global__ void prep_bias(const float* __restrict__ bih,
                          const float* __restrict__ bhh,
                          float* __restrict__ bc) {
    int idx = blockIdx.x * 256 + threadIdx.x;
    int g = idx & 511;
    float scale = (g >= 256 && g < 384) ? (2.0f * LOG2E) : LOG2E;
    bc[idx] = (bih[idx] + bhh[idx]) * scale;
}

// ---------------------------------------------------------------------------
// recur_chunk: wavefront launch w. Block bid=(l<<4)|g is active iff
// k = w - l in [0,NCH): layer l runs chunk k (timesteps k*C .. k*C+C-1).
// All cross-(l,k) ordering comes from launch boundaries: NO atomics/spins.
// Per step: stage input -> raw barrier (lgkm only, no vmcnt drain) ->
// {store h_{t-1} (fire&forget), fc finish (l==3), prefetch t+2} -> MFMA -> cell.
// h ping-pong in LDS (stride 260: conflict-free b128); c in regs per launch,
// persisted in cstate. FC fused into l==3 epilogue (shfl + LDS reduce).
// ---------------------------------------------------------------------------
__global__ __launch_bounds__(512, 2)
void recur_chunk(const ushort* __restrict__ xb,
                 const ushort* __restrict__ Wc,
                 const float* __restrict__ biasc,
                 ushort* __restrict__ ring,     // [3][2] slots of RCHUNK
                 ushort* __restrict__ seed3,    // [B][H] l3 chunk-seed h
                 float*  __restrict__ cstate,   // [NL][16][16][128] f32
                 const float* __restrict__ wfc,
                 const float* __restrict__ bfc,
                 float* __restrict__ out,
                 int wlaunch) {
    __shared__ ushort comb[2][16][STR_];
    __shared__ float  fcbuf[2][16][8];

    const int bid = blockIdx.x;
    const int l = bid >> 4;
    const int g = bid & 15;
    const int k = wlaunch - l;
    if (k < 0 || k >= NCH) return;

    const int kx = (l == 0) ? 96 : 128;
    const int t0 = k * C_;

    const int tid = threadIdx.x;
    const int wv  = tid >> 6;
    const int ln  = tid & 63;
    const int q   = ln >> 4;
    const int lo  = ln & 15;
    const int u   = (wv << 4) | lo;
    const int b0  = g << 4;

    // handoff/staging thread map
    const int crow = tid >> 5;            // 0..15
    const int cu4  = (tid & 31) << 2;     // 0,4,..124
    const int seg  = tid & 31;
    const bool act = (seg < 24);          // layer-0 x staging (24*4=96 cols)

    const ushort* Wl = Wc + (size_t)l * G_ * 256;
    const float*  bl = biasc + l * G_;

    ushort* ring_self = ring + (size_t)(2 * l + (k & 1)) * RCHUNK;            // l<3
    const ushort* ring_up = ring + (size_t)(2 * (l - 1) + (k & 1)) * RCHUNK;  // l>0

    // zero LDS (pad cols must stay 0; h-part default 0 for k==0)
    for (int i = tid; i < 2 * 16 * STR_; i += 512) ((ushort*)comb)[i] = 0;
    __syncthreads();

    // h-seed for k>0: this layer's own h at t0-1
    if (k > 0) {
        u64 hs;
        if (l < 3) {
            const ushort* sp = ring + (size_t)(2 * l + ((k - 1) & 1)) * RCHUNK +
                               (size_t)(C_ - 1) * (B_ * H_) + (size_t)(b0 + crow) * H_ + cu4;
            hs = *(const u64*)sp;
        } else {
            hs = *(const u64*)(seed3 + (size_t)(b0 + crow) * H_ + cu4);
        }
        *(u64*)&comb[0][crow][kx + cu4] = hs;
    }

    // persistent B fragments (weights), VGPR/AGPR-resident
    bf16x8 bw[4][8];
#pragma unroll
    for (int tu = 0; tu < 4; ++tu)
#pragma unroll
        for (int s = 0; s < 8; ++s) {
            const ushort* pp = Wl + ((size_t)((tu << 7) + u) << 8) + (s << 5) + (q << 3);
            bw[tu][s] = *(const bf16x8*)pp;
        }

    const float bv0 = bl[u];
    const float bv1 = bl[128 + u];
    const float bv2 = bl[256 + u];
    const float bv3 = bl[384 + u];
    const float wfcu = wfc[u];
    const float bfc0 = bfc[0];

    // c-state
    f32x4 cc = {0.0f, 0.0f, 0.0f, 0.0f};
    if (k > 0) {
#pragma unroll
        for (int r = 0; r < 4; ++r)
            cc[r] = cstate[(((size_t)(l * 16 + g)) * 16 + (q << 2) + r) * 128 + u];
    }

    // depth-2 input prefetch (whole chunk's inputs exist at launch start)
    uint2 xrc = {0u, 0u}, xrn = {0u, 0u};
    u64 hxc = 0, hxn = 0;
    if (l == 0) {
        if (act) {
            xrc = *(const uint2*)(xb + (size_t)((t0 + 0) * B_ + b0 + crow) * 96 + (seg << 2));
            xrn = *(const uint2*)(xb + (size_t)((t0 + 1) * B_ + b0 + crow) * 96 + (seg << 2));
        }
    } else {
        hxc = *(const u64*)(ring_up + (size_t)0 * (B_ * H_) + (size_t)(b0 + crow) * H_ + cu4);
        hxn = *(const u64*)(ring_up + (size_t)1 * (B_ * H_) + (size_t)(b0 + crow) * H_ + cu4);
    }

    __syncthreads();   // seed + zero visible

    for (int tl = 0; tl < C_; ++tl) {
        const int p = tl & 1;

        // A: stage input for step tl into comb[p] x-part
        if (l == 0) {
            if (act) *(uint2*)&comb[p][crow][seg << 2] = xrc;
        } else {
            *(u64*)&comb[p][crow][cu4] = hxc;
        }

        // raw barrier: order LDS only; globals stay in flight
        asm volatile("s_waitcnt lgkmcnt(0)" ::: "memory");
        __builtin_amdgcn_s_barrier();
        __builtin_amdgcn_sched_barrier(0);

        // store h_{tl-1} (sits in comb[p] h-part), coalesced, fire-and-forget
        if (l < 3 && tl >= 1) {
            u64 hold = *(const u64*)&comb[p][crow][kx + cu4];
            *(u64*)(ring_self + (size_t)(tl - 1) * (B_ * H_) +
                    (size_t)(b0 + crow) * H_ + cu4) = hold;
        }

        // fc finish for t-1 (l==3): one wave reduces cross-wave partials
        if (l == 3 && wv == 0 && ln < 16 && tl >= 1) {
            const float* fb = &fcbuf[(tl - 1) & 1][ln][0];
            f32x4 s0 = *(const f32x4*)fb;
            f32x4 s1 = *(const f32x4*)(fb + 4);
            float s = ((s0[0] + s0[1]) + (s0[2] + s0[3])) +
                      ((s1[0] + s1[1]) + (s1[2] + s1[3])) + bfc0;
            out[(size_t)(b0 + ln) * T_ + (t0 + tl - 1)] =
                rcp_fast(1.0f + exp2_fast(-s * LOG2E));
        }

        // shift prefetch regs; issue load for tl+2
        xrc = xrn; hxc = hxn;
        if (tl + 2 < C_) {
            if (l == 0) {
                if (act) xrn = *(const uint2*)(xb + (size_t)((t0 + tl + 2) * B_ + b0 + crow) * 96 + (seg << 2));
            } else {
                hxn = *(const u64*)(ring_up + (size_t)(tl + 2) * (B_ * H_) +
                                    (size_t)(b0 + crow) * H_ + cu4);
            }
        }

        // D: gates = [x|h] . W^T  (M=16 rows, 4 gate tiles, K=256)
        f32x4 a0 = {bv0, bv0, bv0, bv0};
        f32x4 a1 = {bv1, bv1, bv1, bv1};
        f32x4 a2 = {bv2, bv2, bv2, bv2};
        f32x4 a3 = {bv3, bv3, bv3, bv3};
#pragma unroll
        for (int s = 0; s < 8; ++s) {
            bf16x8 av = *(const bf16x8*)&comb[p][lo][(s << 5) + (q << 3)];
            a0 = __builtin_amdgcn_mfma_f32_16x16x32_bf16(av, bw[0][s], a0, 0, 0, 0);
            a1 = __builtin_amdgcn_mfma_f32_16x16x32_bf16(av, bw[1][s], a1, 0, 0, 0);
            a2 = __builtin_amdgcn_mfma_f32_16x16x32_bf16(av, bw[2][s], a2, 0, 0, 0);
            a3 = __builtin_amdgcn_mfma_f32_16x16x32_bf16(av, bw[3][s], a3, 0, 0, 0);
        }

        // E: cell update; h_t -> comb[p^1] h-part; fc partials (l==3)
        f32x4 pr;
#pragma unroll
        for (int r = 0; r < 4; ++r) {
            float ei = exp2_fast(fminf(-a0[r], 60.0f));
            float ef = exp2_fast(-a1[r]);
            float eg = exp2_fast(fminf(-a2[r], 60.0f));
            float eo = exp2_fast(fminf(-a3[r], 60.0f));
            float rf  = rcp_fast(1.0f + ef);
            float rig = rcp_fast((1.0f + ei) * (1.0f + eg));
            float cn  = __builtin_fmaf(cc[r], rf, (1.0f - eg) * rig);
            cc[r] = cn;
            float ec  = exp2_fast(fminf(-2.88539008177793f * cn, 60.0f));
            float roc = rcp_fast((1.0f + eo) * (1.0f + ec));
            float h_  = (1.0f - ec) * roc;
            comb[p ^ 1][(q << 2) + r][kx + u] = bf16_rn(h_);
            pr[r] = h_ * wfcu;
        }
        if (l == 3) {
#pragma unroll
            for (int r = 0; r < 4; ++r) {
                pr[r] += __shfl_xor(pr[r], 1);
                pr[r] += __shfl_xor(pr[r], 2);
                pr[r] += __shfl_xor(pr[r], 4);
                pr[r] += __shfl_xor(pr[r], 8);
            }
            if (lo == 0) {
#pragma unroll
                for (int r = 0; r < 4; ++r)
                    fcbuf[p][(q << 2) + r][wv] = pr[r];
            }
        }
    }

    // flush: h_{C-1} handoff + last fc + c-state
    asm volatile("s_waitcnt lgkmcnt(0)" ::: "memory");
    __builtin_amdgcn_s_barrier();
    __builtin_amdgcn_sched_barrier(0);

    {
        u64 hold = *(const u64*)&comb[C_ & 1][crow][kx + cu4];
        if (l < 3) {
            *(u64*)(ring_self + (size_t)(C_ - 1) * (B_ * H_) +
                    (size_t)(b0 + crow) * H_ + cu4) = hold;
        } else {
            *(u64*)(seed3 + (size_t)(b0 + crow) * H_ + cu4) = hold;
        }
    }
    if (l == 3 && wv == 0 && ln < 16) {
        const float* fb = &fcbuf[(C_ - 1) & 1][ln][0];
        f32x4 s0 = *(const f32x4*)fb;
        f32x4 s1 = *(const f32x4*)(fb + 4);
        float s = ((s0[0] + s0[1]) + (s0[2] + s0[3])) +
                  ((s1[0] + s1[1]) + (s1[2] + s1[3])) + bfc0;
        out[(size_t)(b0 + ln) * T_ + (t0 + C_ - 1)] =
            rcp_fast(1.0f + exp2_fast(-s * LOG2E));
    }
#pragma unroll
    for (int r = 0; r < 4; ++r)
        cstate[(((size_t)(l * 16 + g)) * 16 + (q << 2) + r) * 128 + u] = cc[r];
}

// ---------------------------------------------------------------------------
extern "C" void kernel_launch(void* const* d_in, const int* in_sizes, int n_in,
                              void* d_out, int out_size, void* d_ws, size_t ws_size,
                              hipStream_t stream) {
    const float* x    = (const float*)d_in[0];
    const float* Wih0 = (const float*)d_in[1];
    const float* Wihr = (const float*)d_in[2];
    const float* Whh  = (const float*)d_in[3];
    const float* bih  = (const float*)d_in[4];
    const float* bhh  = (const float*)d_in[5];
    const float* Wfc  = (const float*)d_in[6];
    const float* bfc  = (const float*)d_in[7];
    float* out = (float*)d_out;

    char* ws = (char*)d_ws;
    const size_t xb_bytes    = (size_t)T_ * B_ * 96 * 2;        // 25,165,824
    const size_t wc_bytes    = (size_t)NL_ * G_ * 256 * 2;      //  1,048,576
    const size_t bias_bytes  = (size_t)NL_ * G_ * 4;            //      8,192
    const size_t ring_bytes  = (size_t)6 * RCHUNK * 2;          // 25,165,824
    const size_t seed3_bytes = (size_t)B_ * H_ * 2;             //     65,536

    ushort* xb    = (ushort*)ws;
    ushort* Wc    = (ushort*)(ws + xb_bytes);
    float*  biasc = (float*)(ws + xb_bytes + wc_bytes);
    ushort* ring  = (ushort*)(ws + xb_bytes + wc_bytes + bias_bytes);
    ushort* seed3 = (ushort*)(ws + xb_bytes + wc_bytes + bias_bytes + ring_bytes);
    float*  cstate= (float*)(ws + xb_bytes + wc_bytes + bias_bytes + ring_bytes + seed3_bytes);

    prep_x<<<(T_ * B_ * 96) / 256, 256, 0, stream>>>(x, xb);
    prep_w<<<(NL_ * G_ * 256) / 256, 256, 0, stream>>>(Wih0, Wihr, Whh, Wc);
    prep_bias<<<(NL_ * G_) / 256, 256, 0, stream>>>(bih, bhh, biasc);

    for (int w = 0; w < NLAUNCH; ++w) {
        recur_chunk<<<NL_ * 16, 512, 0, stream>>>(xb, Wc, biasc, ring, seed3,
                                                  cstate, Wfc, bfc, out, w);
    }
}

// Round 5
// 1137.643 us; speedup vs baseline: 1.0331x; 1.0331x over previous
//
#include <hip/hip_runtime.h>
#include <hip/hip_bf16.h>

// Problem constants
#define H_    128
#define IN_   93
#define NL_   4
#define B_    256
#define T_    512
#define G_    512   // 4*H
#define C_    32    // chunk length (timesteps per launch)
#define NCH   (T_ / C_)          // 16 chunks
#define NLAUNCH (NCH + NL_ - 1)  // 19 wavefront launches
#define LOG2E 1.44269504088896f
#define BH_   (B_ * H_)          // 32768
#define B96_  (B_ * 96)

#define STR_  260   // LDS row stride in ushorts: 130 dwords ≡ 2 (mod 32) -> 2-way banks (free)

typedef __attribute__((ext_vector_type(8))) short bf16x8;
typedef __attribute__((ext_vector_type(4))) float f32x4;
typedef unsigned long long u64;

#define RCHUNK ((size_t)C_ * B_ * H_)   // elems per ring slot (one chunk of h)

__device__ __forceinline__ ushort bf16_rn(float f) {
    uint x = __float_as_uint(f);
    uint r = (x + 0x7FFFu + ((x >> 16) & 1u)) >> 16;
    return (ushort)r;
}
__device__ __forceinline__ float exp2_fast(float x) { return __builtin_amdgcn_exp2f(x); }
__device__ __forceinline__ float rcp_fast(float x)  { return __builtin_amdgcn_rcpf(x); }

// ---------------------------------------------------------------------------
// prep_x: x [B][T][93] f32 -> xb [T][B][96] bf16 (zero-padded)
// ---------------------------------------------------------------------------
__global__ void prep_x(const float* __restrict__ x, ushort* __restrict__ xb) {
    int idx = blockIdx.x * 256 + threadIdx.x;
    int t = idx / (B_ * 96);
    int rem = idx % (B_ * 96);
    int b = rem / 96;
    int k = rem % 96;
    float v = 0.0f;
    if (k < IN_) v = x[((size_t)b * T_ + t) * IN_ + k];
    xb[idx] = bf16_rn(v);
}

// ---------------------------------------------------------------------------
// prep_w: combined prescaled bf16 weights Wc [NL][512][256]
// ---------------------------------------------------------------------------
__global__ void prep_w(const float* __restrict__ Wih0,
                       const float* __restrict__ Wihr,
                       const float* __restrict__ Whh,
                       ushort* __restrict__ Wc) {
    int idx = blockIdx.x * 256 + threadIdx.x;
    int l = idx / (G_ * 256);
    int rem = idx % (G_ * 256);
    int g = rem / 256;
    int k = rem % 256;
    int kx = (l == 0) ? 96 : 128;
    float v = 0.0f;
    if (k < kx) {
        if (l == 0) { if (k < IN_) v = Wih0[g * IN_ + k]; }
        else        { v = Wihr[(((size_t)(l - 1)) * G_ + g) * H_ + k]; }
    } else if (k < kx + H_) {
        v = Whh[(((size_t)l) * G_ + g) * H_ + (k - kx)];
    }
    float scale = (g >= 256 && g < 384) ? (2.0f * LOG2E) : LOG2E;
    Wc[idx] = bf16_rn(v * scale);
}

__global__ void prep_bias(const float* __restrict__ bih,
                          const float* __restrict__ bhh,
                          float* __restrict__ bc) {
    int idx = blockIdx.x * 256 + threadIdx.x;
    int g = idx & 511;
    float scale = (g >= 256 && g < 384) ? (2.0f * LOG2E) : LOG2E;
    bc[idx] = (bih[idx] + bhh[idx]) * scale;
}

// ---------------------------------------------------------------------------
// recur_chunk: wavefront launch w. Block bid=(l<<4)|g active iff k=w-l in
// [0,NCH). Ordering across (l,k) purely from launch boundaries.
// Per step: stage -> raw barrier (lgkm only) -> [hold ds_read; batched A
// ds_reads; global stores/loads with uniform-offset addressing] -> MFMA ->
// cell update (LDS only). All global latency hides under compute.
// ---------------------------------------------------------------------------
__global__ __launch_bounds__(512, 2)
void recur_chunk(const ushort* __restrict__ xb,
                 const ushort* __restrict__ Wc,
                 const float* __restrict__ biasc,
                 ushort* __restrict__ ring,     // [3][2] slots of RCHUNK
                 ushort* __restrict__ seed3,    // [B][H] l3 chunk-seed h
                 float*  __restrict__ cstate,   // [NL][16][16][128] f32
                 const float* __restrict__ wfc,
                 const float* __restrict__ bfc,
                 float* __restrict__ out,
                 int wlaunch) {
    __shared__ ushort comb[2][16][STR_];
    __shared__ float  fcbuf[2][16][8];

    const int bid = blockIdx.x;
    const int l = bid >> 4;
    const int g = bid & 15;
    const int k = wlaunch - l;
    if (k < 0 || k >= NCH) return;

    const int kx = (l == 0) ? 96 : 128;
    const int t0 = k * C_;

    const int tid = threadIdx.x;
    const int wv  = tid >> 6;
    const int ln  = tid & 63;
    const int q   = ln >> 4;
    const int lo  = ln & 15;
    const int u   = (wv << 4) | lo;
    const int b0  = g << 4;

    // handoff/staging thread map
    const int crow = tid >> 5;            // 0..15
    const int cu4  = (tid & 31) << 2;     // 0,4,..124
    const int seg  = tid & 31;
    const bool act = (seg < 24);          // layer-0 x staging (24*4=96 cols)

    const ushort* Wl = Wc + (size_t)l * G_ * 256;
    const float*  bl = biasc + l * G_;

    ushort* ring_self = ring + (size_t)(2 * l + (k & 1)) * RCHUNK;            // l<3
    const ushort* ring_up = ring + (size_t)(2 * (l - 1) + (k & 1)) * RCHUNK;  // l>0

    // per-thread base pointers (computed once; in-loop offsets are uniform ints)
    const ushort* xb_t   = xb + (size_t)(b0 + crow) * 96 + (seg << 2);
    const ushort* hup_t  = ring_up + (size_t)(b0 + crow) * H_ + cu4;
    ushort*       hself_t= ring_self + (size_t)(b0 + crow) * H_ + cu4;
    float*        out_t  = out + (size_t)(b0 + ln) * T_ + t0;

    // zero LDS (pad cols must stay 0; h-part default 0 for k==0)
    for (int i = tid; i < 2 * 16 * STR_; i += 512) ((ushort*)comb)[i] = 0;
    __syncthreads();

    // h-seed for k>0: this layer's own h at t0-1
    if (k > 0) {
        u64 hs;
        if (l < 3) {
            const ushort* sp = ring + (size_t)(2 * l + ((k - 1) & 1)) * RCHUNK +
                               (size_t)(C_ - 1) * BH_ + (size_t)(b0 + crow) * H_ + cu4;
            hs = *(const u64*)sp;
        } else {
            hs = *(const u64*)(seed3 + (size_t)(b0 + crow) * H_ + cu4);
        }
        *(u64*)&comb[0][crow][kx + cu4] = hs;
    }

    // persistent B fragments (weights)
    bf16x8 bw[4][8];
#pragma unroll
    for (int tu = 0; tu < 4; ++tu)
#pragma unroll
        for (int s = 0; s < 8; ++s) {
            const ushort* pp = Wl + ((size_t)((tu << 7) + u) << 8) + (s << 5) + (q << 3);
            bw[tu][s] = *(const bf16x8*)pp;
        }

    const float bv0 = bl[u];
    const float bv1 = bl[128 + u];
    const float bv2 = bl[256 + u];
    const float bv3 = bl[384 + u];
    const float wfcu = wfc[u];
    const float bfc0 = bfc[0];

    // c-state
    f32x4 cc = {0.0f, 0.0f, 0.0f, 0.0f};
    if (k > 0) {
#pragma unroll
        for (int r = 0; r < 4; ++r)
            cc[r] = cstate[(((size_t)(l * 16 + g)) * 16 + (q << 2) + r) * 128 + u];
    }

    // depth-2 input prefetch; uniform int offsets from here on
    uint2 xrc = {0u, 0u}, xrn = {0u, 0u};
    u64 hxc = 0, hxn = 0;
    int xoff = t0 * B96_;          // l==0 load offset (uniform)
    if (l == 0) {
        if (act) {
            xrc = *(const uint2*)(xb_t + xoff);
            xrn = *(const uint2*)(xb_t + xoff + B96_);
        }
        xoff += 2 * B96_;
    } else {
        hxc = *(const u64*)(hup_t);
        hxn = *(const u64*)(hup_t + BH_);
    }
    int uoff = 2 * BH_;            // l>0 prefetch offset (uniform)
    int soff = 0;                  // store offset (uniform)

    __syncthreads();   // seed + zero visible

    for (int tl = 0; tl < C_; ++tl) {
        const int p = tl & 1;

        // A: stage input for step tl into comb[p] x-part
        if (l == 0) {
            if (act) *(uint2*)&comb[p][crow][seg << 2] = xrc;
        } else {
            *(u64*)&comb[p][crow][cu4] = hxc;
        }

        // raw barrier: order LDS only; globals stay in flight
        asm volatile("s_waitcnt lgkmcnt(0)" ::: "memory");
        __builtin_amdgcn_s_barrier();
        __builtin_amdgcn_sched_barrier(0);

        // h_{tl-1} readback first (its lgkm wait then doesn't cover av[])
        u64 hold = 0;
        if (tl >= 1) hold = *(const u64*)&comb[p][crow][kx + cu4];

        // batched A-frag reads: single latency exposure
        bf16x8 av[8];
#pragma unroll
        for (int s = 0; s < 8; ++s)
            av[s] = *(const bf16x8*)&comb[p][lo][(s << 5) + (q << 3)];

        // global phase: fire-and-forget store of h_{tl-1}
        if (l < 3 && tl >= 1) {
            *(u64*)(hself_t + soff) = hold;
            soff += BH_;
        }

        // fc finish for t-1 (l==3): one wave reduces cross-wave partials
        if (l == 3 && wv == 0 && ln < 16 && tl >= 1) {
            const float* fb = &fcbuf[(tl - 1) & 1][ln][0];
            f32x4 s0 = *(const f32x4*)fb;
            f32x4 s1 = *(const f32x4*)(fb + 4);
            float s = ((s0[0] + s0[1]) + (s0[2] + s0[3])) +
                      ((s1[0] + s1[1]) + (s1[2] + s1[3])) + bfc0;
            out_t[tl - 1] = rcp_fast(1.0f + exp2_fast(-s * LOG2E));
        }

        // shift prefetch regs; issue load for tl+2 (uniform-offset addressing)
        xrc = xrn; hxc = hxn;
        if (tl + 2 < C_) {
            if (l == 0) {
                if (act) xrn = *(const uint2*)(xb_t + xoff);
                xoff += B96_;
            } else {
                hxn = *(const u64*)(hup_t + uoff);
                uoff += BH_;
            }
        }

        // D: gates = [x|h] . W^T  (M=16 rows, 4 gate tiles, K=256)
        f32x4 a0 = {bv0, bv0, bv0, bv0};
        f32x4 a1 = {bv1, bv1, bv1, bv1};
        f32x4 a2 = {bv2, bv2, bv2, bv2};
        f32x4 a3 = {bv3, bv3, bv3, bv3};
#pragma unroll
        for (int s = 0; s < 8; ++s) {
            a0 = __builtin_amdgcn_mfma_f32_16x16x32_bf16(av[s], bw[0][s], a0, 0, 0, 0);
            a1 = __builtin_amdgcn_mfma_f32_16x16x32_bf16(av[s], bw[1][s], a1, 0, 0, 0);
            a2 = __builtin_amdgcn_mfma_f32_16x16x32_bf16(av[s], bw[2][s], a2, 0, 0, 0);
            a3 = __builtin_amdgcn_mfma_f32_16x16x32_bf16(av[s], bw[3][s], a3, 0, 0, 0);
        }

        // E: cell update; h_t -> comb[p^1] h-part; fc partials (l==3)
        f32x4 pr;
#pragma unroll
        for (int r = 0; r < 4; ++r) {
            float ei = exp2_fast(fminf(-a0[r], 60.0f));
            float ef = exp2_fast(-a1[r]);
            float eg = exp2_fast(fminf(-a2[r], 60.0f));
            float eo = exp2_fast(fminf(-a3[r], 60.0f));
            float rf  = rcp_fast(1.0f + ef);
            float rig = rcp_fast((1.0f + ei) * (1.0f + eg));
            float cn  = __builtin_fmaf(cc[r], rf, (1.0f - eg) * rig);
            cc[r] = cn;
            float ec  = exp2_fast(fminf(-2.88539008177793f * cn, 60.0f));
            float roc = rcp_fast((1.0f + eo) * (1.0f + ec));
            float h_  = (1.0f - ec) * roc;
            comb[p ^ 1][(q << 2) + r][kx + u] = bf16_rn(h_);
            pr[r] = h_ * wfcu;
        }
        if (l == 3) {
#pragma unroll
            for (int r = 0; r < 4; ++r) {
                pr[r] += __shfl_xor(pr[r], 1);
                pr[r] += __shfl_xor(pr[r], 2);
                pr[r] += __shfl_xor(pr[r], 4);
                pr[r] += __shfl_xor(pr[r], 8);
            }
            if (lo == 0) {
#pragma unroll
                for (int r = 0; r < 4; ++r)
                    fcbuf[p][(q << 2) + r][wv] = pr[r];
            }
        }
    }

    // flush: h_{C-1} handoff + last fc + c-state
    asm volatile("s_waitcnt lgkmcnt(0)" ::: "memory");
    __builtin_amdgcn_s_barrier();
    __builtin_amdgcn_sched_barrier(0);

    {
        u64 hold = *(const u64*)&comb[C_ & 1][crow][kx + cu4];
        if (l < 3) {
            *(u64*)(hself_t + soff) = hold;
        } else {
            *(u64*)(seed3 + (size_t)(b0 + crow) * H_ + cu4) = hold;
        }
    }
    if (l == 3 && wv == 0 && ln < 16) {
        const float* fb = &fcbuf[(C_ - 1) & 1][ln][0];
        f32x4 s0 = *(const f32x4*)fb;
        f32x4 s1 = *(const f32x4*)(fb + 4);
        float s = ((s0[0] + s0[1]) + (s0[2] + s0[3])) +
                  ((s1[0] + s1[1]) + (s1[2] + s1[3])) + bfc0;
        out_t[C_ - 1] = rcp_fast(1.0f + exp2_fast(-s * LOG2E));
    }
#pragma unroll
    for (int r = 0; r < 4; ++r)
        cstate[(((size_t)(l * 16 + g)) * 16 + (q << 2) + r) * 128 + u] = cc[r];
}

// ---------------------------------------------------------------------------
extern "C" void kernel_launch(void* const* d_in, const int* in_sizes, int n_in,
                              void* d_out, int out_size, void* d_ws, size_t ws_size,
                              hipStream_t stream) {
    const float* x    = (const float*)d_in[0];
    const float* Wih0 = (const float*)d_in[1];
    const float* Wihr = (const float*)d_in[2];
    const float* Whh  = (const float*)d_in[3];
    const float* bih  = (const float*)d_in[4];
    const float* bhh  = (const float*)d_in[5];
    const float* Wfc  = (const float*)d_in[6];
    const float* bfc  = (const float*)d_in[7];
    float* out = (float*)d_out;

    char* ws = (char*)d_ws;
    const size_t xb_bytes    = (size_t)T_ * B_ * 96 * 2;        // 25,165,824
    const size_t wc_bytes    = (size_t)NL_ * G_ * 256 * 2;      //  1,048,576
    const size_t bias_bytes  = (size_t)NL_ * G_ * 4;            //      8,192
    const size_t ring_bytes  = (size_t)6 * RCHUNK * 2;          // 12,582,912
    const size_t seed3_bytes = (size_t)B_ * H_ * 2;             //     65,536

    ushort* xb    = (ushort*)ws;
    ushort* Wc    = (ushort*)(ws + xb_bytes);
    float*  biasc = (float*)(ws + xb_bytes + wc_bytes);
    ushort* ring  = (ushort*)(ws + xb_bytes + wc_bytes + bias_bytes);
    ushort* seed3 = (ushort*)(ws + xb_bytes + wc_bytes + bias_bytes + ring_bytes);
    float*  cstate= (float*)(ws + xb_bytes + wc_bytes + bias_bytes + ring_bytes + seed3_bytes);

    prep_x<<<(T_ * B_ * 96) / 256, 256, 0, stream>>>(x, xb);
    prep_w<<<(NL_ * G_ * 256) / 256, 256, 0, stream>>>(Wih0, Wihr, Whh, Wc);
    prep_bias<<<(NL_ * G_) / 256, 256, 0, stream>>>(bih, bhh, biasc);

    for (int w = 0; w < NLAUNCH; ++w) {
        recur_chunk<<<NL_ * 16, 512, 0, stream>>>(xb, Wc, biasc, ring, seed3,
                                                  cstate, Wfc, bfc, out, w);
    }
}